// Round 9
// baseline (770.348 us; speedup 1.0000x reference)
//
#include <hip/hip_runtime.h>
#include <cstdint>
#include <cstddef>

#define N_NODES 100000
#define N_EDGES 1600000

// ---------------- workspace layout (byte offsets) ----------------
#define WS_ROWPTR   0            // (N+1) int
#define WS_DEG      400384       // N int
#define WS_FILL     800768       // N int
#define WS_INVDEG   1201152      // N float
#define WS_BSUM     1601536      // 98 int
#define WS_FLAG     1602560      // 1 int (1 = edge_index is int64)
#define WS_BP       1602816      // 4 x 64KB MFMA-frag-packed W (h 32KB + l 32KB each)
#define WS_WCT2     1864960      // 128x80 f ([k][o], o<40 -> Wl2, o>=40 -> Wr2)
#define WS_COL      1906176      // E int
#define WS_AGG      8306432      // N*128 u32 pack (51.2MB)
#define WS_H1       59506432     // N*128 u32 pack
#define WS_H2       110706432    // N*128 u32 pack
#define WS_P        WS_AGG              // overlay (agg dead after layer-1 GEMM); stride 64 f -> 25.6MB
#define WS_R        (WS_AGG + 25600000) // N*40 f (16MB; 25.6+16 < 51.2MB overlay)

typedef __attribute__((ext_vector_type(8))) short short8;
typedef __attribute__((ext_vector_type(4))) float floatx4;

// split fp32 into bf16 hi/lo, packed (hi in bits 31:16, lo bf16 bits in 15:0)
__device__ __forceinline__ unsigned pack_bf16x2(float x) {
    unsigned u = __float_as_uint(x);
    unsigned hi = (u + 0x7FFFu + ((u >> 16) & 1u)) & 0xFFFF0000u;
    float r = x - __uint_as_float(hi);
    unsigned ur = __float_as_uint(r);
    unsigned lo = (ur + 0x7FFFu + ((ur >> 16) & 1u)) >> 16;
    return hi | lo;
}
// reconstruct: hi + lo (error ~2^-17 relative)
__device__ __forceinline__ float unpk(unsigned u) {
    return __uint_as_float(u & 0xFFFF0000u) + __uint_as_float(u << 16);
}

__device__ __forceinline__ int edge_val(const void* ei, long long idx, int m64) {
    return m64 ? (int)((const long long*)ei)[idx] : ((const int*)ei)[idx];
}

// detect int32 vs int64 edge_index: int64 -> all odd 32-bit words are zero
__global__ void k_detect(const void* __restrict__ ei, int* __restrict__ flag) {
    __shared__ int s_any;
    if (threadIdx.x == 0) s_any = 0;
    __syncthreads();
    const int* p = (const int*)ei;
    int any = 0;
    for (int j = 0; j < 8; ++j) any |= p[2 * (threadIdx.x * 8 + j) + 1];
    if (any) s_any = 1;
    __syncthreads();
    if (threadIdx.x == 0) *flag = (s_any == 0) ? 1 : 0;
}

// WcT2 for layer-2 fp32 GEMM (unchanged path)
__global__ void k_transpose(const float* __restrict__ Wl2, const float* __restrict__ Wr2,
                            float* __restrict__ Tc) {
    int i = blockIdx.x * 256 + threadIdx.x;
    if (i < 10240) {
        int k = i / 80, o = i % 80;
        Tc[i] = (o < 40) ? Wl2[o * 128 + k] : Wr2[(o - 40) * 128 + k];
    }
}

// pack Wl0,Wr0,Wl1,Wr1 into MFMA B-fragment order, bf16 hi/lo planes.
// B[k][n] frag for 16x16x32: lane supplies n=lane&15, k=quad*8+j (j=0..7).
__global__ void k_packw(const float* __restrict__ Wl0, const float* __restrict__ Wr0,
                        const float* __restrict__ Wl1, const float* __restrict__ Wr1,
                        short* __restrict__ bp) {
    int t = blockIdx.x * 256 + threadIdx.x;     // 8192 tasks
    if (t >= 8192) return;
    int mat = t >> 11, rem = t & 2047;
    int kt = rem >> 9, nt = (rem >> 6) & 7, lane = rem & 63;
    const float* W = (mat == 0) ? Wl0 : (mat == 1) ? Wr0 : (mat == 2) ? Wl1 : Wr1;
    int n  = nt * 16 + (lane & 15);
    int kb = kt * 32 + (lane >> 4) * 8;
    short* dh = bp + mat * 32768 + ((size_t)(kt * 8 + nt) * 64 + lane) * 8;
    short* dl = dh + 16384;
    for (int j = 0; j < 8; ++j) {
        unsigned p = pack_bf16x2(W[n * 128 + kb + j]);  // W row-major [o][k]
        dh[j] = (short)(p >> 16);
        dl[j] = (short)(p & 0xFFFFu);
    }
}

__global__ void k_hist(const void* __restrict__ ei, const int* __restrict__ flag,
                       int* __restrict__ deg) {
    int m = *flag;
    int e = blockIdx.x * blockDim.x + threadIdx.x;
    if (e < N_EDGES) {
        int d = edge_val(ei, (long long)N_EDGES + e, m);
        atomicAdd(&deg[d], 1);
    }
}

__global__ void k_scan1(const int* __restrict__ deg, int* __restrict__ bsum) {
    __shared__ int sd[256];
    int t = threadIdx.x;
    int i0 = blockIdx.x * 1024 + t * 4;
    int s = 0;
    #pragma unroll
    for (int j = 0; j < 4; ++j) if (i0 + j < N_NODES) s += deg[i0 + j];
    sd[t] = s; __syncthreads();
    for (int off = 128; off; off >>= 1) {
        if (t < off) sd[t] += sd[t + off];
        __syncthreads();
    }
    if (t == 0) bsum[blockIdx.x] = sd[0];
}

// parallel exclusive scan of the 98 block sums (one block, 128 threads).
// Same LDS scan pattern as k_scan3; bit-exact vs the old serial loop.
__global__ void k_scan2(int* __restrict__ bsum, int* __restrict__ row_ptr, int nb) {
    __shared__ int sd[128];
    int t = threadIdx.x;
    int v = (t < nb) ? bsum[t] : 0;
    sd[t] = v; __syncthreads();
    for (int off = 1; off < 128; off <<= 1) {
        int x = 0;
        if (t >= off) x = sd[t - off];
        __syncthreads();
        sd[t] += x;
        __syncthreads();
    }
    if (t < nb) bsum[t] = sd[t] - v;          // exclusive prefix
    if (t == 127) row_ptr[N_NODES] = sd[127]; // grand total (padding adds 0)
}

__global__ void k_scan3(const int* __restrict__ deg, const int* __restrict__ bsum,
                        int* __restrict__ row_ptr) {
    __shared__ int sd[256];
    int t = threadIdx.x;
    int i0 = blockIdx.x * 1024 + t * 4;
    int v[4]; int s = 0;
    #pragma unroll
    for (int j = 0; j < 4; ++j) { v[j] = (i0 + j < N_NODES) ? deg[i0 + j] : 0; s += v[j]; }
    sd[t] = s; __syncthreads();
    for (int off = 1; off < 256; off <<= 1) {
        int x = 0;
        if (t >= off) x = sd[t - off];
        __syncthreads();
        sd[t] += x;
        __syncthreads();
    }
    int run = bsum[blockIdx.x] + sd[t] - s;
    #pragma unroll
    for (int j = 0; j < 4; ++j) {
        if (i0 + j < N_NODES) row_ptr[i0 + j] = run;
        run += v[j];
    }
}

__global__ void k_invdeg(const int* __restrict__ row_ptr, float* __restrict__ invd) {
    int i = blockIdx.x * 256 + threadIdx.x;
    if (i < N_NODES) {
        int d = row_ptr[i + 1] - row_ptr[i];
        invd[i] = 1.0f / (float)(d > 1 ? d : 1);
    }
}

__global__ void k_scatter(const void* __restrict__ ei, const int* __restrict__ flag,
                          const int* __restrict__ row_ptr, int* __restrict__ fill,
                          int* __restrict__ col) {
    int m = *flag;
    int e = blockIdx.x * blockDim.x + threadIdx.x;
    if (e < N_EDGES) {
        int s = edge_val(ei, e, m);
        int d = edge_val(ei, (long long)N_EDGES + e, m);
        int pos = row_ptr[d] + atomicAdd(&fill[d], 1);
        col[pos] = s;
    }
}

// mean-aggregate, packed input, HALF-FEATURE pass: lane covers feature fo+lane
// (1 u32), per-pass row footprint 256B -> per-XCD L2 working set halves.
// Per-feature edge order and pairwise add tree identical to the full kernel
// -> bit-identical output across the two passes.
__global__ __launch_bounds__(256) void k_aggregate_h(
    const unsigned* __restrict__ h, const int* __restrict__ rowp,
    const int* __restrict__ col, const float* __restrict__ invd,
    unsigned* __restrict__ agg, int fo) {
    int w = blockIdx.x * 4 + (threadIdx.x >> 6);
    if (w >= N_NODES) return;
    int f = fo + (threadIdx.x & 63);
    int beg = rowp[w], end = rowp[w + 1];
    float x = 0.f;
    int e = beg;
    for (; e + 8 <= end; e += 8) {
        int s0 = col[e], s1 = col[e + 1], s2 = col[e + 2], s3 = col[e + 3];
        int s4 = col[e + 4], s5 = col[e + 5], s6 = col[e + 6], s7 = col[e + 7];
        float a  = unpk(h[(size_t)s0 * 128 + f]);
        float b  = unpk(h[(size_t)s1 * 128 + f]);
        float c  = unpk(h[(size_t)s2 * 128 + f]);
        float d  = unpk(h[(size_t)s3 * 128 + f]);
        float a2 = unpk(h[(size_t)s4 * 128 + f]);
        float b2 = unpk(h[(size_t)s5 * 128 + f]);
        float c2 = unpk(h[(size_t)s6 * 128 + f]);
        float d2 = unpk(h[(size_t)s7 * 128 + f]);
        x += (a + b) + (c + d) + (a2 + b2) + (c2 + d2);
    }
    for (; e < end; ++e) x += unpk(h[(size_t)col[e] * 128 + f]);
    agg[(size_t)w * 128 + f] = pack_bf16x2(x * invd[w]);
}

// layer-0 fp32 variant, HALF-FEATURE pass (same order; no pack round-trip)
__global__ __launch_bounds__(256) void k_aggregate_xh(
    const float* __restrict__ xin, const int* __restrict__ rowp,
    const int* __restrict__ col, const float* __restrict__ invd,
    unsigned* __restrict__ agg, int fo) {
    int w = blockIdx.x * 4 + (threadIdx.x >> 6);
    if (w >= N_NODES) return;
    int f = fo + (threadIdx.x & 63);
    int beg = rowp[w], end = rowp[w + 1];
    float x = 0.f;
    int e = beg;
    for (; e + 8 <= end; e += 8) {
        int s0 = col[e], s1 = col[e + 1], s2 = col[e + 2], s3 = col[e + 3];
        int s4 = col[e + 4], s5 = col[e + 5], s6 = col[e + 6], s7 = col[e + 7];
        float a  = xin[(size_t)s0 * 128 + f];
        float b  = xin[(size_t)s1 * 128 + f];
        float c  = xin[(size_t)s2 * 128 + f];
        float d  = xin[(size_t)s3 * 128 + f];
        float a2 = xin[(size_t)s4 * 128 + f];
        float b2 = xin[(size_t)s5 * 128 + f];
        float c2 = xin[(size_t)s6 * 128 + f];
        float d2 = xin[(size_t)s7 * 128 + f];
        x += (a + b) + (c + d) + (a2 + b2) + (c2 + d2);
    }
    for (; e < end; ++e) x += xin[(size_t)col[e] * 128 + f];
    agg[(size_t)w * 128 + f] = pack_bf16x2(x * invd[w]);
}

// bf16x3 MFMA GEMM: out = relu(l2norm(agg@WlT + h@WrT + b)), packed u32 I/O.
// v9: B panels LDS-double-buffered (v8) AND A fragments register-prefetched
// one panel ahead (uniform uint4 carriers, converted at use per-phase) -> the
// per-panel A-load latency hides under 24 MFMAs + barrier instead of draining
// right before use. Numerics bit-identical (same fragments, same MFMA order).
// F32H: H-side (ph=1) reads raw fp32 rows and packs hi/lo on the fly.
// C/D: col(n)=lane&15, row(m)=quad*4+reg [m89-verified]. Epilogue l2norm via
// quad-shuffles, LDS transpose (per-wave private region, after a barrier).
template<bool F32H>
__global__ __launch_bounds__(256) void k_gemm_mfma(
    const unsigned* __restrict__ Vpack, const void* __restrict__ Hsrc,
    const short* __restrict__ BL, const short* __restrict__ BR,
    const float* __restrict__ bias, unsigned* __restrict__ outp) {
    __shared__ unsigned sE[4 * 2048];   // 32 KB: 2x16KB B panels; epilogue 8KB/wave
    const int t = threadIdx.x, lane = t & 63, wv = t >> 6;
    const int mrow = lane & 15, kq = lane >> 4;
    int nb = blockIdx.x * 64 + wv * 16;
    if (nb > N_NODES - 16) nb = N_NODES - 16;   // tail: duplicate recompute, benign

    floatx4 acc[8];
    #pragma unroll
    for (int nt = 0; nt < 8; ++nt) {
        float bv = bias[nt * 16 + mrow];
        floatx4 b4 = {bv, bv, bv, bv};
        acc[nt] = b4;
    }

    const size_t rbase = (size_t)(nb + mrow) * 128 + kq * 8;
    uint4* sB = (uint4*)sE;                   // buf0: uint4[0..1023], buf1: [1024..2047]
    // prologue: stage panel 0 (BL, kt=0) and A(p=0) (ph=0 -> Vpack)
    uint4 a0c, a1c;
    {
        const uint4* gh = (const uint4*)BL;
        const uint4* gl = (const uint4*)(BL + 16384);
        uint4 r0 = gh[t], r1 = gh[t + 256], r2 = gl[t], r3 = gl[t + 256];
        const unsigned* ap = Vpack + rbase;
        a0c = *(const uint4*)ap; a1c = *(const uint4*)(ap + 4);
        sB[t] = r0; sB[t + 256] = r1; sB[t + 512] = r2; sB[t + 768] = r3;
    }
    __syncthreads();

    #pragma unroll
    for (int p = 0; p < 8; ++p) {
        const int ph = p >> 2;
        // issue next panel's B loads + next A loads early (hide under MFMAs)
        uint4 r0, r1, r2, r3, a0n, a1n;
        if (p < 7) {
            const int pn = p + 1, phn = pn >> 2, ktn = pn & 3;
            const short* Bs = phn ? BR : BL;
            const uint4* gh = (const uint4*)(Bs + ktn * 4096);
            const uint4* gl = (const uint4*)(Bs + 16384 + ktn * 4096);
            r0 = gh[t]; r1 = gh[t + 256]; r2 = gl[t]; r3 = gl[t + 256];
            const size_t roffn = rbase + ktn * 32;
            if (F32H && phn == 1) {
                const float* fp = (const float*)Hsrc + roffn;
                a0n = *(const uint4*)fp; a1n = *(const uint4*)(fp + 4);
            } else {
                const unsigned* ap = (phn ? (const unsigned*)Hsrc : Vpack) + roffn;
                a0n = *(const uint4*)ap; a1n = *(const uint4*)(ap + 4);
            }
        }
        // build A fragments from current carriers
        short8 Ah, Al;
        {
            unsigned ua[8] = {a0c.x, a0c.y, a0c.z, a0c.w, a1c.x, a1c.y, a1c.z, a1c.w};
            if (F32H && ph == 1) {
                #pragma unroll
                for (int j = 0; j < 8; ++j) {
                    unsigned pk = pack_bf16x2(__uint_as_float(ua[j]));
                    Ah[j] = (short)(pk >> 16);
                    Al[j] = (short)(pk & 0xFFFFu);
                }
            } else {
                #pragma unroll
                for (int j = 0; j < 8; ++j) {
                    Ah[j] = (short)(ua[j] >> 16);
                    Al[j] = (short)(ua[j] & 0xFFFFu);
                }
            }
        }
        // MFMA panel p from current buffer
        const short8* sBc = (const short8*)(sB + (p & 1) * 1024);
        #pragma unroll
        for (int nt = 0; nt < 8; ++nt) {
            short8 bh = sBc[nt * 64 + lane];
            short8 bl = sBc[512 + nt * 64 + lane];
            acc[nt] = __builtin_amdgcn_mfma_f32_16x16x32_bf16(Ah, bh, acc[nt], 0, 0, 0);
            acc[nt] = __builtin_amdgcn_mfma_f32_16x16x32_bf16(Ah, bl, acc[nt], 0, 0, 0);
            acc[nt] = __builtin_amdgcn_mfma_f32_16x16x32_bf16(Al, bh, acc[nt], 0, 0, 0);
        }
        if (p < 7) {
            __syncthreads();                  // all waves done reading target buffer's old panel
            uint4* sBn = sB + ((p + 1) & 1) * 1024;
            sBn[t] = r0; sBn[t + 256] = r1; sBn[t + 512] = r2; sBn[t + 768] = r3;
            a0c = a0n; a1c = a1n;
            __syncthreads();                  // panel p+1 visible
        }
    }
    __syncthreads();   // main loop done before epilogue reuses sE

    // epilogue: l2norm rows, relu, pack, per-wave LDS transpose, store (16 rows)
    unsigned* myE = sE + wv * 2048;
    float ss[4] = {0.f, 0.f, 0.f, 0.f};
    #pragma unroll
    for (int nt = 0; nt < 8; ++nt)
        #pragma unroll
        for (int r = 0; r < 4; ++r) ss[r] += acc[nt][r] * acc[nt][r];
    #pragma unroll
    for (int m = 1; m < 16; m <<= 1) {
        #pragma unroll
        for (int r = 0; r < 4; ++r) ss[r] += __shfl_xor(ss[r], m, 64);
    }
    float sc[4];
    #pragma unroll
    for (int r = 0; r < 4; ++r) sc[r] = 1.f / fmaxf(sqrtf(ss[r]), 1e-12f);
    #pragma unroll
    for (int nt = 0; nt < 8; ++nt)
        #pragma unroll
        for (int r = 0; r < 4; ++r) {
            float v = fmaxf(acc[nt][r] * sc[r], 0.f);
            myE[(kq * 4 + r) * 128 + nt * 16 + mrow] = pack_bf16x2(v);
        }
    __builtin_amdgcn_wave_barrier();
    #pragma unroll
    for (int i = 0; i < 8; ++i) {
        int row = i * 2 + (lane >> 5);
        int colw = (lane & 31) * 4;
        uint4 d = *(const uint4*)(myE + row * 128 + colw);
        *(uint4*)(outp + (size_t)(nb + row) * 128 + colw) = d;
    }
}

// layer 2: P = h@Wl2T ; R = h@Wr2T + b2 (80 outs, cat-W in LDS), packed-u32 input.
// P stored with stride 64 (256B, line-aligned rows) for the k_final gather.
__global__ __launch_bounds__(320, 2) void k_gemm2(
    const unsigned* __restrict__ h, const float* __restrict__ WcatT,
    const float* __restrict__ b2, float* __restrict__ P, float* __restrict__ R) {
    __shared__ float sW[128 * 80];
    const int t = threadIdx.x;
    const int o4 = (t % 20) * 4;
    const int ng = t / 20;
    const int nb = blockIdx.x * 128 + ng * 8;
    #pragma unroll
    for (int j = 0; j < 8; ++j)
        ((float4*)sW)[t + 320 * j] = ((const float4*)WcatT)[t + 320 * j];
    __syncthreads();
    float4 binit = make_float4(0.f, 0.f, 0.f, 0.f);
    if (o4 >= 40) binit = *(const float4*)(b2 + (o4 - 40));
    float acc[8][4];
    #pragma unroll
    for (int j = 0; j < 8; ++j) { acc[j][0] = binit.x; acc[j][1] = binit.y; acc[j][2] = binit.z; acc[j][3] = binit.w; }
    const uint4* vrow[8];
    #pragma unroll
    for (int j = 0; j < 8; ++j) {
        int n = nb + j; n = n < N_NODES ? n : N_NODES - 1;
        vrow[j] = (const uint4*)(h + (size_t)n * 128);
    }
    #pragma unroll 4
    for (int kq = 0; kq < 32; ++kq) {
        const int k = kq * 4;
        float4 w0 = *(const float4*)(sW + (k + 0) * 80 + o4);
        float4 w1 = *(const float4*)(sW + (k + 1) * 80 + o4);
        float4 w2 = *(const float4*)(sW + (k + 2) * 80 + o4);
        float4 w3 = *(const float4*)(sW + (k + 3) * 80 + o4);
        #pragma unroll
        for (int j = 0; j < 8; ++j) {
            uint4 u = vrow[j][kq];
            float4 v = make_float4(unpk(u.x), unpk(u.y), unpk(u.z), unpk(u.w));
            acc[j][0] = fmaf(v.x, w0.x, fmaf(v.y, w1.x, fmaf(v.z, w2.x, fmaf(v.w, w3.x, acc[j][0]))));
            acc[j][1] = fmaf(v.x, w0.y, fmaf(v.y, w1.y, fmaf(v.z, w2.y, fmaf(v.w, w3.y, acc[j][1]))));
            acc[j][2] = fmaf(v.x, w0.z, fmaf(v.y, w1.z, fmaf(v.z, w2.z, fmaf(v.w, w3.z, acc[j][2]))));
            acc[j][3] = fmaf(v.x, w0.w, fmaf(v.y, w1.w, fmaf(v.z, w2.w, fmaf(v.w, w3.w, acc[j][3]))));
        }
    }
    #pragma unroll
    for (int j = 0; j < 8; ++j) {
        int n = nb + j;
        if (n < N_NODES) {
            float4 r = make_float4(acc[j][0], acc[j][1], acc[j][2], acc[j][3]);
            if (o4 < 40) *(float4*)(P + (size_t)n * 64 + o4) = r;
            else         *(float4*)(R + (size_t)n * 40 + (o4 - 40)) = r;
        }
    }
}

// final: logits = mean_agg(P[src]) + R; softmax over 40; one wave per node.
// 8 edges per iteration (8 loads in flight) with 8 accumulators.
// P rows stride-64 (256B aligned, 2 lines).
__global__ __launch_bounds__(256) void k_final(
    const float* __restrict__ P, const float* __restrict__ R,
    const int* __restrict__ rowp, const int* __restrict__ col,
    const float* __restrict__ invd, float* __restrict__ out) {
    int w = blockIdx.x * 4 + (threadIdx.x >> 6);
    if (w >= N_NODES) return;
    int lane = threadIdx.x & 63;
    bool act = lane < 40;
    int beg = rowp[w], end = rowp[w + 1];
    float a0 = 0.f, a1 = 0.f, a2 = 0.f, a3 = 0.f;
    float a4 = 0.f, a5 = 0.f, a6 = 0.f, a7 = 0.f;
    int e = beg;
    for (; e + 8 <= end; e += 8) {
        int s0 = col[e],     s1 = col[e + 1], s2 = col[e + 2], s3 = col[e + 3];
        int s4 = col[e + 4], s5 = col[e + 5], s6 = col[e + 6], s7 = col[e + 7];
        if (act) {
            float f0 = P[(size_t)s0 * 64 + lane];
            float f1 = P[(size_t)s1 * 64 + lane];
            float f2 = P[(size_t)s2 * 64 + lane];
            float f3 = P[(size_t)s3 * 64 + lane];
            float f4 = P[(size_t)s4 * 64 + lane];
            float f5 = P[(size_t)s5 * 64 + lane];
            float f6 = P[(size_t)s6 * 64 + lane];
            float f7 = P[(size_t)s7 * 64 + lane];
            a0 += f0; a1 += f1; a2 += f2; a3 += f3;
            a4 += f4; a5 += f5; a6 += f6; a7 += f7;
        }
    }
    for (; e + 4 <= end; e += 4) {
        int s0 = col[e], s1 = col[e + 1], s2 = col[e + 2], s3 = col[e + 3];
        if (act) {
            a0 += P[(size_t)s0 * 64 + lane];
            a1 += P[(size_t)s1 * 64 + lane];
            a2 += P[(size_t)s2 * 64 + lane];
            a3 += P[(size_t)s3 * 64 + lane];
        }
    }
    for (; e < end; ++e) if (act) a0 += P[(size_t)col[e] * 64 + lane];
    float acc = ((a0 + a1) + (a2 + a3)) + ((a4 + a5) + (a6 + a7));
    float v = act ? (acc * invd[w] + R[(size_t)w * 40 + lane]) : -1e30f;
    float m = v;
    #pragma unroll
    for (int off = 32; off; off >>= 1) m = fmaxf(m, __shfl_xor(m, off, 64));
    float ex = act ? expf(v - m) : 0.f;
    float s = ex;
    #pragma unroll
    for (int off = 32; off; off >>= 1) s += __shfl_xor(s, off, 64);
    if (act) out[(size_t)w * 40 + lane] = ex / s;
}

extern "C" void kernel_launch(void* const* d_in, const int* in_sizes, int n_in,
                              void* d_out, int out_size, void* d_ws, size_t ws_size,
                              hipStream_t stream) {
    const float* x   = (const float*)d_in[0];
    const void*  ei  = d_in[1];
    const float* Wl0 = (const float*)d_in[2];
    const float* Wr0 = (const float*)d_in[3];
    const float* b0  = (const float*)d_in[4];
    const float* Wl1 = (const float*)d_in[5];
    const float* Wr1 = (const float*)d_in[6];
    const float* b1  = (const float*)d_in[7];
    const float* Wl2 = (const float*)d_in[8];
    const float* Wr2 = (const float*)d_in[9];
    const float* b2  = (const float*)d_in[10];
    float* out = (float*)d_out;

    char* ws = (char*)d_ws;
    int*      row_ptr = (int*)(ws + WS_ROWPTR);
    int*      deg     = (int*)(ws + WS_DEG);
    int*      fill    = (int*)(ws + WS_FILL);
    float*    invd    = (float*)(ws + WS_INVDEG);
    int*      bsum    = (int*)(ws + WS_BSUM);
    int*      flag    = (int*)(ws + WS_FLAG);
    short*    bp      = (short*)(ws + WS_BP);
    float*    WcT2    = (float*)(ws + WS_WCT2);
    int*      col     = (int*)(ws + WS_COL);
    unsigned* aggp    = (unsigned*)(ws + WS_AGG);
    unsigned* h1p     = (unsigned*)(ws + WS_H1);
    unsigned* h2p     = (unsigned*)(ws + WS_H2);
    float*    P       = (float*)(ws + WS_P);
    float*    R       = (float*)(ws + WS_R);

    hipMemsetAsync(ws + WS_DEG, 0, 800768, stream);

    k_detect<<<1, 256, 0, stream>>>(ei, flag);
    k_transpose<<<40, 256, 0, stream>>>(Wl2, Wr2, WcT2);
    k_packw<<<32, 256, 0, stream>>>(Wl0, Wr0, Wl1, Wr1, bp);
    k_hist<<<N_EDGES / 256, 256, 0, stream>>>(ei, flag, deg);
    k_scan1<<<98, 256, 0, stream>>>(deg, bsum);
    k_scan2<<<1, 128, 0, stream>>>(bsum, row_ptr, 98);
    k_scan3<<<98, 256, 0, stream>>>(deg, bsum, row_ptr);
    k_invdeg<<<391, 256, 0, stream>>>(row_ptr, invd);
    k_scatter<<<N_EDGES / 256, 256, 0, stream>>>(ei, flag, row_ptr, fill, col);

    // layer 0 (fp32 x, two half-feature passes; no pack_x round-trip)
    k_aggregate_xh<<<25000, 256, 0, stream>>>(x, row_ptr, col, invd, aggp, 0);
    k_aggregate_xh<<<25000, 256, 0, stream>>>(x, row_ptr, col, invd, aggp, 64);
    k_gemm_mfma<true><<<1563, 256, 0, stream>>>(aggp, (const void*)x, bp, bp + 32768, b0, h1p);
    // layer 1 (packed h1, two half-feature passes)
    k_aggregate_h<<<25000, 256, 0, stream>>>(h1p, row_ptr, col, invd, aggp, 0);
    k_aggregate_h<<<25000, 256, 0, stream>>>(h1p, row_ptr, col, invd, aggp, 64);
    k_gemm_mfma<false><<<1563, 256, 0, stream>>>(aggp, (const void*)h1p, bp + 2 * 32768, bp + 3 * 32768, b1, h2p);
    // layer 2 (GEMM first, then aggregate the 40-dim projections)
    k_gemm2<<<782, 320, 0, stream>>>(h2p, WcT2, b2, P, R);
    k_final<<<25000, 256, 0, stream>>>(P, R, row_ptr, col, invd, out);
}

// Round 10
// 649.771 us; speedup vs baseline: 1.1856x; 1.1856x over previous
//
#include <hip/hip_runtime.h>
#include <cstdint>
#include <cstddef>

#define N_NODES 100000
#define N_EDGES 1600000

// ---------------- workspace layout (byte offsets) ----------------
#define WS_ROWPTR   0            // (N+1) int
#define WS_DEG      400384       // N int
#define WS_FILL     800768       // N int
#define WS_INVDEG   1201152      // N float
#define WS_BSUM     1601536      // 98 int
#define WS_FLAG     1602560      // 1 int (1 = edge_index is int64)
#define WS_BP       1602816      // 4 x 64KB MFMA-frag-packed W (h 32KB + l 32KB each)
#define WS_BP2      1864960      // 40KB MFMA-frag-packed Wl2||Wr2 (hi 20KB + lo 20KB)
#define WS_COL      1906176      // E int
#define WS_AGG      8306432      // N*128 u32 pack (51.2MB)
#define WS_H1       59506432     // N*128 u32 pack
#define WS_H2       110706432    // N*128 u32 pack
#define WS_P        WS_AGG              // overlay (agg dead after layer-1 GEMM); stride 64 f -> 25.6MB
#define WS_R        (WS_AGG + 25600000) // N*40 f (16MB; 25.6+16 < 51.2MB overlay)

typedef __attribute__((ext_vector_type(8))) short short8;
typedef __attribute__((ext_vector_type(4))) float floatx4;

// split fp32 into bf16 hi/lo, packed (hi in bits 31:16, lo bf16 bits in 15:0)
__device__ __forceinline__ unsigned pack_bf16x2(float x) {
    unsigned u = __float_as_uint(x);
    unsigned hi = (u + 0x7FFFu + ((u >> 16) & 1u)) & 0xFFFF0000u;
    float r = x - __uint_as_float(hi);
    unsigned ur = __float_as_uint(r);
    unsigned lo = (ur + 0x7FFFu + ((ur >> 16) & 1u)) >> 16;
    return hi | lo;
}
// reconstruct: hi + lo (error ~2^-17 relative)
__device__ __forceinline__ float unpk(unsigned u) {
    return __uint_as_float(u & 0xFFFF0000u) + __uint_as_float(u << 16);
}

__device__ __forceinline__ int edge_val(const void* ei, long long idx, int m64) {
    return m64 ? (int)((const long long*)ei)[idx] : ((const int*)ei)[idx];
}

// detect int32 vs int64 edge_index: int64 -> all odd 32-bit words are zero
__global__ void k_detect(const void* __restrict__ ei, int* __restrict__ flag) {
    __shared__ int s_any;
    if (threadIdx.x == 0) s_any = 0;
    __syncthreads();
    const int* p = (const int*)ei;
    int any = 0;
    for (int j = 0; j < 8; ++j) any |= p[2 * (threadIdx.x * 8 + j) + 1];
    if (any) s_any = 1;
    __syncthreads();
    if (threadIdx.x == 0) *flag = (s_any == 0) ? 1 : 0;
}

// pack Wl0,Wr0,Wl1,Wr1 into MFMA B-fragment order, bf16 hi/lo planes.
// B[k][n] frag for 16x16x32: lane supplies n=lane&15, k=quad*8+j (j=0..7).
__global__ void k_packw(const float* __restrict__ Wl0, const float* __restrict__ Wr0,
                        const float* __restrict__ Wl1, const float* __restrict__ Wr1,
                        short* __restrict__ bp) {
    int t = blockIdx.x * 256 + threadIdx.x;     // 8192 tasks
    if (t >= 8192) return;
    int mat = t >> 11, rem = t & 2047;
    int kt = rem >> 9, nt = (rem >> 6) & 7, lane = rem & 63;
    const float* W = (mat == 0) ? Wl0 : (mat == 1) ? Wr0 : (mat == 2) ? Wl1 : Wr1;
    int n  = nt * 16 + (lane & 15);
    int kb = kt * 32 + (lane >> 4) * 8;
    short* dh = bp + mat * 32768 + ((size_t)(kt * 8 + nt) * 64 + lane) * 8;
    short* dl = dh + 16384;
    for (int j = 0; j < 8; ++j) {
        unsigned p = pack_bf16x2(W[n * 128 + kb + j]);  // W row-major [o][k]
        dh[j] = (short)(p >> 16);
        dl[j] = (short)(p & 0xFFFFu);
    }
}

// pack Wl2||Wr2 (80 outs x 128) into B-fragments, 5 n-tiles x 4 k-tiles,
// same layout convention as k_packw. hi plane 10240 shorts, lo follows.
__global__ void k_packw2(const float* __restrict__ Wl2, const float* __restrict__ Wr2,
                         short* __restrict__ bp2) {
    int t = blockIdx.x * 256 + threadIdx.x;     // 1280 tasks
    if (t >= 1280) return;
    int kt = t / 320, rem = t % 320;
    int nt = rem / 64, lane = rem % 64;
    int n  = nt * 16 + (lane & 15);             // out index 0..79
    int kb = kt * 32 + (lane >> 4) * 8;
    const float* W = (n < 40) ? (Wl2 + (size_t)n * 128) : (Wr2 + (size_t)(n - 40) * 128);
    short* dh = bp2 + ((size_t)(kt * 5 + nt) * 64 + lane) * 8;
    short* dl = dh + 10240;
    for (int j = 0; j < 8; ++j) {
        unsigned p = pack_bf16x2(W[kb + j]);
        dh[j] = (short)(p >> 16);
        dl[j] = (short)(p & 0xFFFFu);
    }
}

// v10: 4 edges/thread (block covers 1024 consecutive edges, stride-256 for
// per-instruction coalescing) -> 4 independent latency chains per thread.
__global__ void k_hist(const void* __restrict__ ei, const int* __restrict__ flag,
                       int* __restrict__ deg) {
    int m = *flag;
    int base = blockIdx.x * 1024 + threadIdx.x;
    #pragma unroll
    for (int j = 0; j < 4; ++j) {
        int e = base + j * 256;
        if (e < N_EDGES) {
            int d = edge_val(ei, (long long)N_EDGES + e, m);
            atomicAdd(&deg[d], 1);
        }
    }
}

__global__ void k_scan1(const int* __restrict__ deg, int* __restrict__ bsum) {
    __shared__ int sd[256];
    int t = threadIdx.x;
    int i0 = blockIdx.x * 1024 + t * 4;
    int s = 0;
    #pragma unroll
    for (int j = 0; j < 4; ++j) if (i0 + j < N_NODES) s += deg[i0 + j];
    sd[t] = s; __syncthreads();
    for (int off = 128; off; off >>= 1) {
        if (t < off) sd[t] += sd[t + off];
        __syncthreads();
    }
    if (t == 0) bsum[blockIdx.x] = sd[0];
}

// parallel exclusive scan of the 98 block sums (one block, 128 threads).
__global__ void k_scan2(int* __restrict__ bsum, int* __restrict__ row_ptr, int nb) {
    __shared__ int sd[128];
    int t = threadIdx.x;
    int v = (t < nb) ? bsum[t] : 0;
    sd[t] = v; __syncthreads();
    for (int off = 1; off < 128; off <<= 1) {
        int x = 0;
        if (t >= off) x = sd[t - off];
        __syncthreads();
        sd[t] += x;
        __syncthreads();
    }
    if (t < nb) bsum[t] = sd[t] - v;          // exclusive prefix
    if (t == 127) row_ptr[N_NODES] = sd[127]; // grand total (padding adds 0)
}

__global__ void k_scan3(const int* __restrict__ deg, const int* __restrict__ bsum,
                        int* __restrict__ row_ptr) {
    __shared__ int sd[256];
    int t = threadIdx.x;
    int i0 = blockIdx.x * 1024 + t * 4;
    int v[4]; int s = 0;
    #pragma unroll
    for (int j = 0; j < 4; ++j) { v[j] = (i0 + j < N_NODES) ? deg[i0 + j] : 0; s += v[j]; }
    sd[t] = s; __syncthreads();
    for (int off = 1; off < 256; off <<= 1) {
        int x = 0;
        if (t >= off) x = sd[t - off];
        __syncthreads();
        sd[t] += x;
        __syncthreads();
    }
    int run = bsum[blockIdx.x] + sd[t] - s;
    #pragma unroll
    for (int j = 0; j < 4; ++j) {
        if (i0 + j < N_NODES) row_ptr[i0 + j] = run;
        run += v[j];
    }
}

__global__ void k_invdeg(const int* __restrict__ row_ptr, float* __restrict__ invd) {
    int i = blockIdx.x * 256 + threadIdx.x;
    if (i < N_NODES) {
        int d = row_ptr[i + 1] - row_ptr[i];
        invd[i] = 1.0f / (float)(d > 1 ? d : 1);
    }
}

// v10: 4 edges/thread, independent chains
__global__ void k_scatter(const void* __restrict__ ei, const int* __restrict__ flag,
                          const int* __restrict__ row_ptr, int* __restrict__ fill,
                          int* __restrict__ col) {
    int m = *flag;
    int base = blockIdx.x * 1024 + threadIdx.x;
    #pragma unroll
    for (int j = 0; j < 4; ++j) {
        int e = base + j * 256;
        if (e < N_EDGES) {
            int s = edge_val(ei, e, m);
            int d = edge_val(ei, (long long)N_EDGES + e, m);
            int pos = row_ptr[d] + atomicAdd(&fill[d], 1);
            col[pos] = s;
        }
    }
}

// mean-aggregate packed rows: one wave per node, uint2 (2 packed cols) per lane
// (round-0/8 verified structure: 8-edge batches, 24 VGPR, ~74% occupancy)
__global__ __launch_bounds__(256) void k_aggregate(
    const unsigned* __restrict__ h, const int* __restrict__ rowp,
    const int* __restrict__ col, const float* __restrict__ invd,
    unsigned* __restrict__ agg) {
    int w = blockIdx.x * 4 + (threadIdx.x >> 6);
    if (w >= N_NODES) return;
    int lane = threadIdx.x & 63;
    const uint2* hp = (const uint2*)h;
    int beg = rowp[w], end = rowp[w + 1];
    float x = 0.f, y = 0.f;
    int e = beg;
    for (; e + 8 <= end; e += 8) {
        int s0 = col[e], s1 = col[e + 1], s2 = col[e + 2], s3 = col[e + 3];
        int s4 = col[e + 4], s5 = col[e + 5], s6 = col[e + 6], s7 = col[e + 7];
        uint2 a = hp[(size_t)s0 * 64 + lane];
        uint2 b = hp[(size_t)s1 * 64 + lane];
        uint2 c = hp[(size_t)s2 * 64 + lane];
        uint2 d = hp[(size_t)s3 * 64 + lane];
        uint2 a2 = hp[(size_t)s4 * 64 + lane];
        uint2 b2 = hp[(size_t)s5 * 64 + lane];
        uint2 c2 = hp[(size_t)s6 * 64 + lane];
        uint2 d2 = hp[(size_t)s7 * 64 + lane];
        x += (unpk(a.x) + unpk(b.x)) + (unpk(c.x) + unpk(d.x))
           + (unpk(a2.x) + unpk(b2.x)) + (unpk(c2.x) + unpk(d2.x));
        y += (unpk(a.y) + unpk(b.y)) + (unpk(c.y) + unpk(d.y))
           + (unpk(a2.y) + unpk(b2.y)) + (unpk(c2.y) + unpk(d2.y));
    }
    for (; e < end; ++e) {
        uint2 a = hp[(size_t)col[e] * 64 + lane];
        x += unpk(a.x); y += unpk(a.y);
    }
    float id = invd[w];
    ((uint2*)agg)[(size_t)w * 64 + lane] =
        make_uint2(pack_bf16x2(x * id), pack_bf16x2(y * id));
}

// layer-0 variant: gather raw fp32 x rows directly (same addresses/add order)
__global__ __launch_bounds__(256) void k_aggregate_x(
    const float* __restrict__ xin, const int* __restrict__ rowp,
    const int* __restrict__ col, const float* __restrict__ invd,
    unsigned* __restrict__ agg) {
    int w = blockIdx.x * 4 + (threadIdx.x >> 6);
    if (w >= N_NODES) return;
    int lane = threadIdx.x & 63;
    const float2* hp = (const float2*)xin;
    int beg = rowp[w], end = rowp[w + 1];
    float x = 0.f, y = 0.f;
    int e = beg;
    for (; e + 8 <= end; e += 8) {
        int s0 = col[e], s1 = col[e + 1], s2 = col[e + 2], s3 = col[e + 3];
        int s4 = col[e + 4], s5 = col[e + 5], s6 = col[e + 6], s7 = col[e + 7];
        float2 a = hp[(size_t)s0 * 64 + lane];
        float2 b = hp[(size_t)s1 * 64 + lane];
        float2 c = hp[(size_t)s2 * 64 + lane];
        float2 d = hp[(size_t)s3 * 64 + lane];
        float2 a2 = hp[(size_t)s4 * 64 + lane];
        float2 b2 = hp[(size_t)s5 * 64 + lane];
        float2 c2 = hp[(size_t)s6 * 64 + lane];
        float2 d2 = hp[(size_t)s7 * 64 + lane];
        x += (a.x + b.x) + (c.x + d.x) + (a2.x + b2.x) + (c2.x + d2.x);
        y += (a.y + b.y) + (c.y + d.y) + (a2.y + b2.y) + (c2.y + d2.y);
    }
    for (; e < end; ++e) {
        float2 a = hp[(size_t)col[e] * 64 + lane];
        x += a.x; y += a.y;
    }
    float id = invd[w];
    ((uint2*)agg)[(size_t)w * 64 + lane] =
        make_uint2(pack_bf16x2(x * id), pack_bf16x2(y * id));
}

// bf16x3 MFMA GEMM: out = relu(l2norm(agg@WlT + h@WrT + b)), packed u32 I/O.
// v9 structure: B panels LDS-double-buffered AND A fragments register-
// prefetched one panel ahead. Bit-identical numerics to v6-v9.
template<bool F32H>
__global__ __launch_bounds__(256) void k_gemm_mfma(
    const unsigned* __restrict__ Vpack, const void* __restrict__ Hsrc,
    const short* __restrict__ BL, const short* __restrict__ BR,
    const float* __restrict__ bias, unsigned* __restrict__ outp) {
    __shared__ unsigned sE[4 * 2048];   // 32 KB: 2x16KB B panels; epilogue 8KB/wave
    const int t = threadIdx.x, lane = t & 63, wv = t >> 6;
    const int mrow = lane & 15, kq = lane >> 4;
    int nb = blockIdx.x * 64 + wv * 16;
    if (nb > N_NODES - 16) nb = N_NODES - 16;   // tail: duplicate recompute, benign

    floatx4 acc[8];
    #pragma unroll
    for (int nt = 0; nt < 8; ++nt) {
        float bv = bias[nt * 16 + mrow];
        floatx4 b4 = {bv, bv, bv, bv};
        acc[nt] = b4;
    }

    const size_t rbase = (size_t)(nb + mrow) * 128 + kq * 8;
    uint4* sB = (uint4*)sE;                   // buf0: uint4[0..1023], buf1: [1024..2047]
    uint4 a0c, a1c;
    {
        const uint4* gh = (const uint4*)BL;
        const uint4* gl = (const uint4*)(BL + 16384);
        uint4 r0 = gh[t], r1 = gh[t + 256], r2 = gl[t], r3 = gl[t + 256];
        const unsigned* ap = Vpack + rbase;
        a0c = *(const uint4*)ap; a1c = *(const uint4*)(ap + 4);
        sB[t] = r0; sB[t + 256] = r1; sB[t + 512] = r2; sB[t + 768] = r3;
    }
    __syncthreads();

    #pragma unroll
    for (int p = 0; p < 8; ++p) {
        const int ph = p >> 2;
        uint4 r0, r1, r2, r3, a0n, a1n;
        if (p < 7) {
            const int pn = p + 1, phn = pn >> 2, ktn = pn & 3;
            const short* Bs = phn ? BR : BL;
            const uint4* gh = (const uint4*)(Bs + ktn * 4096);
            const uint4* gl = (const uint4*)(Bs + 16384 + ktn * 4096);
            r0 = gh[t]; r1 = gh[t + 256]; r2 = gl[t]; r3 = gl[t + 256];
            const size_t roffn = rbase + ktn * 32;
            if (F32H && phn == 1) {
                const float* fp = (const float*)Hsrc + roffn;
                a0n = *(const uint4*)fp; a1n = *(const uint4*)(fp + 4);
            } else {
                const unsigned* ap = (phn ? (const unsigned*)Hsrc : Vpack) + roffn;
                a0n = *(const uint4*)ap; a1n = *(const uint4*)(ap + 4);
            }
        }
        short8 Ah, Al;
        {
            unsigned ua[8] = {a0c.x, a0c.y, a0c.z, a0c.w, a1c.x, a1c.y, a1c.z, a1c.w};
            if (F32H && ph == 1) {
                #pragma unroll
                for (int j = 0; j < 8; ++j) {
                    unsigned pk = pack_bf16x2(__uint_as_float(ua[j]));
                    Ah[j] = (short)(pk >> 16);
                    Al[j] = (short)(pk & 0xFFFFu);
                }
            } else {
                #pragma unroll
                for (int j = 0; j < 8; ++j) {
                    Ah[j] = (short)(ua[j] >> 16);
                    Al[j] = (short)(ua[j] & 0xFFFFu);
                }
            }
        }
        const short8* sBc = (const short8*)(sB + (p & 1) * 1024);
        #pragma unroll
        for (int nt = 0; nt < 8; ++nt) {
            short8 bh = sBc[nt * 64 + lane];
            short8 bl = sBc[512 + nt * 64 + lane];
            acc[nt] = __builtin_amdgcn_mfma_f32_16x16x32_bf16(Ah, bh, acc[nt], 0, 0, 0);
            acc[nt] = __builtin_amdgcn_mfma_f32_16x16x32_bf16(Ah, bl, acc[nt], 0, 0, 0);
            acc[nt] = __builtin_amdgcn_mfma_f32_16x16x32_bf16(Al, bh, acc[nt], 0, 0, 0);
        }
        if (p < 7) {
            __syncthreads();
            uint4* sBn = sB + ((p + 1) & 1) * 1024;
            sBn[t] = r0; sBn[t + 256] = r1; sBn[t + 512] = r2; sBn[t + 768] = r3;
            a0c = a0n; a1c = a1n;
            __syncthreads();
        }
    }
    __syncthreads();

    // epilogue: l2norm rows, relu, pack, per-wave LDS transpose, store (16 rows)
    unsigned* myE = sE + wv * 2048;
    float ss[4] = {0.f, 0.f, 0.f, 0.f};
    #pragma unroll
    for (int nt = 0; nt < 8; ++nt)
        #pragma unroll
        for (int r = 0; r < 4; ++r) ss[r] += acc[nt][r] * acc[nt][r];
    #pragma unroll
    for (int m = 1; m < 16; m <<= 1) {
        #pragma unroll
        for (int r = 0; r < 4; ++r) ss[r] += __shfl_xor(ss[r], m, 64);
    }
    float sc[4];
    #pragma unroll
    for (int r = 0; r < 4; ++r) sc[r] = 1.f / fmaxf(sqrtf(ss[r]), 1e-12f);
    #pragma unroll
    for (int nt = 0; nt < 8; ++nt)
        #pragma unroll
        for (int r = 0; r < 4; ++r) {
            float v = fmaxf(acc[nt][r] * sc[r], 0.f);
            myE[(kq * 4 + r) * 128 + nt * 16 + mrow] = pack_bf16x2(v);
        }
    __builtin_amdgcn_wave_barrier();
    #pragma unroll
    for (int i = 0; i < 8; ++i) {
        int row = i * 2 + (lane >> 5);
        int colw = (lane & 31) * 4;
        uint4 d = *(const uint4*)(myE + row * 128 + colw);
        *(uint4*)(outp + (size_t)(nb + row) * 128 + colw) = d;
    }
}

// layer 2 as MFMA: [P|R](80 outs) = h2 @ [Wl2|Wr2]^T (+b2 on R side).
// B (40KB bf16 hi/lo fragments) staged once in LDS, shared by 4 waves.
// Wave = 16 nodes; 5 n-tiles; 4 k-tiles; bf16x3 like layers 0/1.
// Epilogue: transpose via LDS (B region, dead after sync), write P stride-64.
__global__ __launch_bounds__(256) void k_gemm2_mfma(
    const unsigned* __restrict__ h2, const short* __restrict__ bp2,
    const float* __restrict__ b2, float* __restrict__ P, float* __restrict__ R) {
    __shared__ unsigned sE[10240];      // 40 KB
    const int t = threadIdx.x, lane = t & 63, wv = t >> 6;
    const int mrow = lane & 15, kq = lane >> 4;
    int nb = blockIdx.x * 64 + wv * 16;
    if (nb > N_NODES - 16) nb = N_NODES - 16;   // tail: duplicate recompute, benign

    // stage all B fragments (2560 uint4)
    {
        const uint4* g = (const uint4*)bp2;
        uint4* s = (uint4*)sE;
        #pragma unroll
        for (int i = 0; i < 10; ++i) s[t + 256 * i] = g[t + 256 * i];
    }
    // A carriers for all 4 k-tiles (issued before the sync; latency overlaps)
    const unsigned* ap = h2 + (size_t)(nb + mrow) * 128 + kq * 8;
    uint4 a0[4], a1[4];
    #pragma unroll
    for (int kt = 0; kt < 4; ++kt) {
        a0[kt] = *(const uint4*)(ap + kt * 32);
        a1[kt] = *(const uint4*)(ap + kt * 32 + 4);
    }

    floatx4 acc[5];
    #pragma unroll
    for (int nt = 0; nt < 5; ++nt) {
        int o = nt * 16 + mrow;
        float bv = (o >= 40) ? b2[o - 40] : 0.f;
        floatx4 b4 = {bv, bv, bv, bv};
        acc[nt] = b4;
    }
    __syncthreads();

    const short8* sB8 = (const short8*)sE;
    #pragma unroll
    for (int kt = 0; kt < 4; ++kt) {
        short8 Ah, Al;
        unsigned ua[8] = {a0[kt].x, a0[kt].y, a0[kt].z, a0[kt].w,
                          a1[kt].x, a1[kt].y, a1[kt].z, a1[kt].w};
        #pragma unroll
        for (int j = 0; j < 8; ++j) {
            Ah[j] = (short)(ua[j] >> 16);
            Al[j] = (short)(ua[j] & 0xFFFFu);
        }
        #pragma unroll
        for (int nt = 0; nt < 5; ++nt) {
            short8 bh = sB8[(size_t)(kt * 5 + nt) * 64 + lane];
            short8 bl = sB8[1280 + (size_t)(kt * 5 + nt) * 64 + lane];
            acc[nt] = __builtin_amdgcn_mfma_f32_16x16x32_bf16(Ah, bh, acc[nt], 0, 0, 0);
            acc[nt] = __builtin_amdgcn_mfma_f32_16x16x32_bf16(Ah, bl, acc[nt], 0, 0, 0);
            acc[nt] = __builtin_amdgcn_mfma_f32_16x16x32_bf16(Al, bh, acc[nt], 0, 0, 0);
        }
    }
    __syncthreads();   // B dead; reuse LDS for per-wave transpose

    float* sT = (float*)sE + wv * 1280;    // 16 nodes x 80 outs
    #pragma unroll
    for (int nt = 0; nt < 5; ++nt)
        #pragma unroll
        for (int r = 0; r < 4; ++r)
            sT[(kq * 4 + r) * 80 + nt * 16 + mrow] = acc[nt][r];
    __builtin_amdgcn_wave_barrier();
    #pragma unroll
    for (int i = 0; i < 5; ++i) {
        int idx = i * 64 + lane;           // 0..319
        int node = idx / 20, q = idx % 20;
        float4 v = *(const float4*)(sT + node * 80 + q * 4);
        if (q < 10) *(float4*)(P + (size_t)(nb + node) * 64 + q * 4) = v;
        else        *(float4*)(R + (size_t)(nb + node) * 40 + (q - 10) * 4) = v;
    }
}

// final: logits = mean_agg(P[src]) + R; softmax over 40; one wave per node.
// 8 edges per iteration (8 loads in flight) with 8 accumulators.
// P rows stride-64 (256B aligned, 2 lines).
__global__ __launch_bounds__(256) void k_final(
    const float* __restrict__ P, const float* __restrict__ R,
    const int* __restrict__ rowp, const int* __restrict__ col,
    const float* __restrict__ invd, float* __restrict__ out) {
    int w = blockIdx.x * 4 + (threadIdx.x >> 6);
    if (w >= N_NODES) return;
    int lane = threadIdx.x & 63;
    bool act = lane < 40;
    int beg = rowp[w], end = rowp[w + 1];
    float a0 = 0.f, a1 = 0.f, a2 = 0.f, a3 = 0.f;
    float a4 = 0.f, a5 = 0.f, a6 = 0.f, a7 = 0.f;
    int e = beg;
    for (; e + 8 <= end; e += 8) {
        int s0 = col[e],     s1 = col[e + 1], s2 = col[e + 2], s3 = col[e + 3];
        int s4 = col[e + 4], s5 = col[e + 5], s6 = col[e + 6], s7 = col[e + 7];
        if (act) {
            float f0 = P[(size_t)s0 * 64 + lane];
            float f1 = P[(size_t)s1 * 64 + lane];
            float f2 = P[(size_t)s2 * 64 + lane];
            float f3 = P[(size_t)s3 * 64 + lane];
            float f4 = P[(size_t)s4 * 64 + lane];
            float f5 = P[(size_t)s5 * 64 + lane];
            float f6 = P[(size_t)s6 * 64 + lane];
            float f7 = P[(size_t)s7 * 64 + lane];
            a0 += f0; a1 += f1; a2 += f2; a3 += f3;
            a4 += f4; a5 += f5; a6 += f6; a7 += f7;
        }
    }
    for (; e + 4 <= end; e += 4) {
        int s0 = col[e], s1 = col[e + 1], s2 = col[e + 2], s3 = col[e + 3];
        if (act) {
            a0 += P[(size_t)s0 * 64 + lane];
            a1 += P[(size_t)s1 * 64 + lane];
            a2 += P[(size_t)s2 * 64 + lane];
            a3 += P[(size_t)s3 * 64 + lane];
        }
    }
    for (; e < end; ++e) if (act) a0 += P[(size_t)col[e] * 64 + lane];
    float acc = ((a0 + a1) + (a2 + a3)) + ((a4 + a5) + (a6 + a7));
    float v = act ? (acc * invd[w] + R[(size_t)w * 40 + lane]) : -1e30f;
    float m = v;
    #pragma unroll
    for (int off = 32; off; off >>= 1) m = fmaxf(m, __shfl_xor(m, off, 64));
    float ex = act ? expf(v - m) : 0.f;
    float s = ex;
    #pragma unroll
    for (int off = 32; off; off >>= 1) s += __shfl_xor(s, off, 64);
    if (act) out[(size_t)w * 40 + lane] = ex / s;
}

extern "C" void kernel_launch(void* const* d_in, const int* in_sizes, int n_in,
                              void* d_out, int out_size, void* d_ws, size_t ws_size,
                              hipStream_t stream) {
    const float* x   = (const float*)d_in[0];
    const void*  ei  = d_in[1];
    const float* Wl0 = (const float*)d_in[2];
    const float* Wr0 = (const float*)d_in[3];
    const float* b0  = (const float*)d_in[4];
    const float* Wl1 = (const float*)d_in[5];
    const float* Wr1 = (const float*)d_in[6];
    const float* b1  = (const float*)d_in[7];
    const float* Wl2 = (const float*)d_in[8];
    const float* Wr2 = (const float*)d_in[9];
    const float* b2  = (const float*)d_in[10];
    float* out = (float*)d_out;

    char* ws = (char*)d_ws;
    int*      row_ptr = (int*)(ws + WS_ROWPTR);
    int*      deg     = (int*)(ws + WS_DEG);
    int*      fill    = (int*)(ws + WS_FILL);
    float*    invd    = (float*)(ws + WS_INVDEG);
    int*      bsum    = (int*)(ws + WS_BSUM);
    int*      flag    = (int*)(ws + WS_FLAG);
    short*    bp      = (short*)(ws + WS_BP);
    short*    bp2     = (short*)(ws + WS_BP2);
    int*      col     = (int*)(ws + WS_COL);
    unsigned* aggp    = (unsigned*)(ws + WS_AGG);
    unsigned* h1p     = (unsigned*)(ws + WS_H1);
    unsigned* h2p     = (unsigned*)(ws + WS_H2);
    float*    P       = (float*)(ws + WS_P);
    float*    R       = (float*)(ws + WS_R);

    hipMemsetAsync(ws + WS_DEG, 0, 800768, stream);

    k_detect<<<1, 256, 0, stream>>>(ei, flag);
    k_packw<<<32, 256, 0, stream>>>(Wl0, Wr0, Wl1, Wr1, bp);
    k_packw2<<<5, 256, 0, stream>>>(Wl2, Wr2, bp2);
    k_hist<<<1563, 256, 0, stream>>>(ei, flag, deg);
    k_scan1<<<98, 256, 0, stream>>>(deg, bsum);
    k_scan2<<<1, 128, 0, stream>>>(bsum, row_ptr, 98);
    k_scan3<<<98, 256, 0, stream>>>(deg, bsum, row_ptr);
    k_invdeg<<<391, 256, 0, stream>>>(row_ptr, invd);
    k_scatter<<<1563, 256, 0, stream>>>(ei, flag, row_ptr, fill, col);

    // layer 0 (x consumed directly in fp32: no pack_x round-trip)
    k_aggregate_x<<<25000, 256, 0, stream>>>(x, row_ptr, col, invd, aggp);
    k_gemm_mfma<true><<<1563, 256, 0, stream>>>(aggp, (const void*)x, bp, bp + 32768, b0, h1p);
    // layer 1
    k_aggregate<<<25000, 256, 0, stream>>>(h1p, row_ptr, col, invd, aggp);
    k_gemm_mfma<false><<<1563, 256, 0, stream>>>(aggp, (const void*)h1p, bp + 2 * 32768, bp + 3 * 32768, b1, h2p);
    // layer 2 (MFMA GEMM, then aggregate the 40-dim projections)
    k_gemm2_mfma<<<1563, 256, 0, stream>>>(h2p, bp2, b2, P, R);
    k_final<<<25000, 256, 0, stream>>>(P, R, row_ptr, col, invd, out);
}